// Round 12
// baseline (23.030 us; speedup 1.0000x reference)
//
#include <hip/hip_runtime.h>

#define PN 131072
#define PH 1024
#define G 128
#define GPTS (G * G)
#define GLO   (-5.0f)
#define GSTEP (10.0f / 127.0f)
#define GINV  (127.0f / 10.0f)
#define XMAX  4.9f            // beyond this -> direct-eval fallback

// Catmull-Rom weights for t in [0,1)
static __device__ __forceinline__ void cr_w(float t, float w[4]) {
    w[0] = t * (-0.5f + t * (1.0f - 0.5f * t));
    w[1] = 1.0f + t * t * (-2.5f + 1.5f * t);
    w[2] = t * (0.5f + t * (2.0f - 1.5f * t));
    w[3] = t * t * (-0.5f + 0.5f * t);
}

// ===== K1: grid_eval over fixed range, prep folded into LDS =====
// 512 blocks x 1024 threads; 32 points/block -> 2 blocks/CU = 8 waves/SIMD.
// 16 waves each own a wave-uniform 64-h chunk; lane halves (sub = lane>>5)
// process the chunk's two 32-h halves (2-distinct-address LDS broadcast = free).
__global__ __launch_bounds__(1024) void grid_eval_kernel(const float* __restrict__ W1,
                                                         const float* __restrict__ b1,
                                                         const float* __restrict__ w2,
                                                         const float* __restrict__ b2p,
                                                         float4* __restrict__ gridout) {
    __shared__ float4 pkA[PH];        // {SC*w10, SC*w11, SC*b1, w2}
    __shared__ float4 pkB[PH];        // {w10*w2, w11*w2, w11^2*w2, 0}
    __shared__ float4 red[16][32];
    __shared__ float sred[16];
    __shared__ float sfb;

    const int bid = blockIdx.x, tid = threadIdx.x;
    const int lane = tid & 63, wv = tid >> 6;
    const int wvu = __builtin_amdgcn_readfirstlane(wv);
    const float SC = 2.8853900817779268f;   // 2*log2(e)

    // ---- prep: thread t handles h = t ----
    {
        const int h = tid;
        const float w10 = W1[2 * h], w11 = W1[2 * h + 1];
        const float w2h = w2[h], b1h = b1[h];
        const float c2 = w11 * w2h;
        pkA[h] = make_float4(w10 * SC, w11 * SC, b1h * SC, w2h);
        pkB[h] = make_float4(w10 * w2h, c2, w11 * c2, 0.0f);
        float ws = w2h;
        #pragma unroll
        for (int m = 32; m >= 1; m >>= 1) ws += __shfl_xor(ws, m, 64);
        if (lane == 0) sred[wv] = ws;
    }
    __syncthreads();
    if (tid == 0) {
        float s = 0.f;
        #pragma unroll
        for (int w = 0; w < 16; ++w) s += sred[w];
        sfb = s + b2p[0];             // sum(w2) + b2
    }
    __syncthreads();

    const int pt = lane & 31;                 // point within block
    const int p  = bid * 32 + pt;             // grid point index
    const int ix = p & (G - 1);
    const int iy = p >> 7;
    const float x0 = __builtin_fmaf((float)ix, GSTEP, GLO);
    const float x1 = __builtin_fmaf((float)iy, GSTEP, GLO);

    const int sub = lane >> 5;                // which 32-h half of the chunk
    const float4* __restrict__ pA = &pkA[wvu * 64 + sub * 32];
    const float4* __restrict__ pB = &pkB[wvu * 64 + sub * 32];

    float a_r = 0.f, a_u1 = 0.f, a_u2 = 0.f, a_u3 = 0.f, a_u4 = 0.f;

    #pragma unroll 4
    for (int j = 0; j < 16; ++j) {
        const float4 Aa = pA[2 * j];
        const float4 Ab = pA[2 * j + 1];
        const float4 Ba = pB[2 * j];
        const float4 Bb = pB[2 * j + 1];

        float zsa = __builtin_fmaf(x0, Aa.x, __builtin_fmaf(x1, Aa.y, Aa.z));
        float zsb = __builtin_fmaf(x0, Ab.x, __builtin_fmaf(x1, Ab.y, Ab.z));
        zsa = fminf(zsa, 40.0f);
        zsb = fminf(zsb, 40.0f);
        const float ea = __builtin_amdgcn_exp2f(zsa);
        const float eb = __builtin_amdgcn_exp2f(zsb);
        const float da = ea + 1.0f;
        const float db = eb + 1.0f;
        const float rab = __builtin_amdgcn_rcpf(da * db);
        const float ra = rab * db;                       // 1/(1+e^{2za})
        const float rb = rab * da;
        const float ua = __builtin_fmaf(-ra, ra, ra);    // r - r^2
        const float ub = __builtin_fmaf(-rb, rb, rb);
        const float rua = ra * ua;
        const float rub = rb * ub;

        a_r  = __builtin_fmaf(ra,  Aa.w, a_r);
        a_r  = __builtin_fmaf(rb,  Ab.w, a_r);
        a_u1 = __builtin_fmaf(ua,  Ba.x, a_u1);
        a_u1 = __builtin_fmaf(ub,  Bb.x, a_u1);
        a_u2 = __builtin_fmaf(ua,  Ba.y, a_u2);
        a_u2 = __builtin_fmaf(ub,  Bb.y, a_u2);
        a_u3 = __builtin_fmaf(ua,  Ba.z, a_u3);
        a_u3 = __builtin_fmaf(ub,  Bb.z, a_u3);
        a_u4 = __builtin_fmaf(rua, Ba.z, a_u4);
        a_u4 = __builtin_fmaf(rub, Bb.z, a_u4);
    }
    float aD = a_u3 - 2.0f * a_u4;    // sum t*u*w11^2*w2 over this half-chunk

    // combine the two 32-h halves (lane <-> lane^32)
    a_r  += __shfl_xor(a_r,  32, 64);
    a_u1 += __shfl_xor(a_u1, 32, 64);
    a_u2 += __shfl_xor(a_u2, 32, 64);
    aD   += __shfl_xor(aD,   32, 64);

    if (lane < 32) red[wv][pt] = make_float4(a_r, a_u1, a_u2, aD);
    __syncthreads();
    if (tid < 32) {
        float4 s = red[0][tid];
        #pragma unroll
        for (int w = 1; w < 16; ++w) {
            const float4 o = red[w][tid];
            s.x += o.x; s.y += o.y; s.z += o.z; s.w += o.w;
        }
        // f = sum w2*(1-2r) + b2 ; df_dt = 4*sum u*w10*w2 ; df_dx = 4*sum u*w11*w2
        // df_dxdx = -8 * sum t*u*w11^2*w2
        const float f   = sfb - 2.0f * s.x;
        const float ft  = 4.0f * s.y;
        const float fx  = 4.0f * s.z;
        const float fxx = -8.0f * s.w;
        gridout[bid * 32 + tid] = make_float4(f, ft, fx, fxx);
    }
}

// ===== K2: bicubic interp + wave-cooperative direct fallback for outliers =====
__global__ __launch_bounds__(256) void interp_kernel(const float2* __restrict__ x2,
                                                     const float4* __restrict__ grid,
                                                     const float* __restrict__ W1,
                                                     const float* __restrict__ b1,
                                                     const float* __restrict__ w2,
                                                     const float* __restrict__ b2p,
                                                     float* __restrict__ out) {
    const int i = blockIdx.x * 256 + threadIdx.x;
    const float2 xv = x2[i];

    float u = (xv.x - GLO) * GINV;
    float v = (xv.y - GLO) * GINV;
    u = fminf(fmaxf(u, 0.0f), (float)(G - 1) - 1e-3f);
    v = fminf(fmaxf(v, 0.0f), (float)(G - 1) - 1e-3f);
    int iu = (int)u;  iu = iu > G - 2 ? G - 2 : iu;
    int iv = (int)v;  iv = iv > G - 2 ? G - 2 : iv;
    const float fu = u - (float)iu;
    const float fv = v - (float)iv;

    float wu[4], wv_[4];
    cr_w(fu, wu);
    cr_w(fv, wv_);

    const int ju0 = iu - 1 < 0 ? 0 : iu - 1;
    const int ju3 = iu + 2 > G - 1 ? G - 1 : iu + 2;
    const int jv0 = iv - 1 < 0 ? 0 : iv - 1;
    const int jv3 = iv + 2 > G - 1 ? G - 1 : iv + 2;
    const int rows[4] = { jv0 * G, iv * G, (iv + 1) * G, jv3 * G };

    float af = 0.f, at = 0.f, ax = 0.f, axx = 0.f;
    #pragma unroll
    for (int r = 0; r < 4; ++r) {
        const int base = rows[r];
        const float4 g0 = grid[base + ju0];
        const float4 g1 = grid[base + iu];
        const float4 g2 = grid[base + iu + 1];
        const float4 g3 = grid[base + ju3];
        const float rf  = wu[0] * g0.x + wu[1] * g1.x + wu[2] * g2.x + wu[3] * g3.x;
        const float rt  = wu[0] * g0.y + wu[1] * g1.y + wu[2] * g2.y + wu[3] * g3.y;
        const float rx  = wu[0] * g0.z + wu[1] * g1.z + wu[2] * g2.z + wu[3] * g3.z;
        const float rxx = wu[0] * g0.w + wu[1] * g1.w + wu[2] * g2.w + wu[3] * g3.w;
        af  = __builtin_fmaf(wv_[r], rf,  af);
        at  = __builtin_fmaf(wv_[r], rt,  at);
        ax  = __builtin_fmaf(wv_[r], rx,  ax);
        axx = __builtin_fmaf(wv_[r], rxx, axx);
    }

    // --- fallback: any lane outside the accurate table region gets an exact
    // direct evaluation, computed cooperatively by the whole wave. ---
    const bool outl = (fabsf(xv.x) > XMAX) || (fabsf(xv.y) > XMAX);
    unsigned long long mball = __ballot(outl);
    if (mball) {
        const int lane = threadIdx.x & 63;
        const float SC = 2.8853900817779268f;
        const float b2v = b2p[0];
        while (mball) {
            const int l = (int)__ffsll((unsigned long long)mball) - 1;
            mball &= mball - 1;
            const float fx0 = __shfl(xv.x, l, 64);
            const float fx1 = __shfl(xv.y, l, 64);
            float s_f = 0.f, s1 = 0.f, s2 = 0.f, s3 = 0.f, s4 = 0.f;
            for (int k = 0; k < 16; ++k) {
                const int h = lane * 16 + k;
                const float w10 = W1[2 * h], w11 = W1[2 * h + 1];
                const float b1h = b1[h], w2h = w2[h];
                float zs = SC * __builtin_fmaf(fx0, w10, __builtin_fmaf(fx1, w11, b1h));
                zs = fminf(zs, 40.0f);
                const float e = __builtin_amdgcn_exp2f(zs);
                const float r = __builtin_amdgcn_rcpf(e + 1.0f);
                const float t = __builtin_fmaf(-2.0f, r, 1.0f);
                const float uq = __builtin_fmaf(-r, r, r);
                const float ru = r * uq;
                const float c1 = w10 * w2h, c2 = w11 * w2h, c3 = w11 * c2;
                s_f += t * w2h;
                s1 = __builtin_fmaf(uq, c1, s1);
                s2 = __builtin_fmaf(uq, c2, s2);
                s3 = __builtin_fmaf(uq, c3, s3);
                s4 = __builtin_fmaf(ru, c3, s4);
            }
            #pragma unroll
            for (int m = 32; m >= 1; m >>= 1) {
                s_f += __shfl_xor(s_f, m, 64);
                s1  += __shfl_xor(s1,  m, 64);
                s2  += __shfl_xor(s2,  m, 64);
                s3  += __shfl_xor(s3,  m, 64);
                s4  += __shfl_xor(s4,  m, 64);
            }
            if (lane == l) {
                af  = s_f + b2v;
                at  = 4.0f * s1;
                ax  = 4.0f * s2;
                axx = -8.0f * (s3 - 2.0f * s4);
            }
        }
    }

    const float x1 = xv.y;
    const float pde = __builtin_fmaf(0.5f * x1, x1, at)
                    + 0.5f * axx
                    + 0.5f * x1 * ax
                    - 0.069444444444444445f * ax * ax;
    out[i] = af;
    out[PN + i] = pde;
}

extern "C" void kernel_launch(void* const* d_in, const int* in_sizes, int n_in,
                              void* d_out, int out_size, void* d_ws, size_t ws_size,
                              hipStream_t stream) {
    const float* x  = (const float*)d_in[0];
    const float* W1 = (const float*)d_in[1];
    const float* b1 = (const float*)d_in[2];
    const float* w2 = (const float*)d_in[3];
    const float* b2 = (const float*)d_in[4];
    float* out = (float*)d_out;
    float4* grid = (float4*)d_ws;      // G*G float4 = 256 KiB

    grid_eval_kernel<<<GPTS / 32, 1024, 0, stream>>>(W1, b1, w2, b2, grid);
    interp_kernel<<<PN / 256, 256, 0, stream>>>((const float2*)x, grid,
                                                W1, b1, w2, b2, out);
}